// Round 12
// baseline (3190.219 us; speedup 1.0000x reference)
//
#include <hip/hip_runtime.h>

typedef __attribute__((ext_vector_type(8))) _Float16 half8;
typedef __attribute__((ext_vector_type(4))) float f32x4;

#define HH 64
#define TT 12
#define TOUT 12
#define CC 10
#define BNTOT 131072

__device__ __forceinline__ float sigm(float x){
  return __builtin_amdgcn_rcpf(1.0f + __expf(-x));
}
__device__ __forceinline__ float tanh_f(float x){
  return 1.0f - 2.0f * __builtin_amdgcn_rcpf(1.0f + __expf(2.0f * x));
}

struct W {
  const float* ewih; const float* ewhh; const float* ebih; const float* ebhh;
  const float* dwih; const float* dwhh; const float* dbih; const float* dbhh;
  const float* l1w;  const float* l1b;  const float* l2w;  const float* l2b;
  const float* emb;
};

#define MFMAH(A,B,C) __builtin_amdgcn_mfma_f32_16x16x32_f16((A),(B),(C),0,0,0)

// group a (0..11) -> w_hh row base: a0-3 pre_r, a4-7 pre_z, a8-11 gh_n
__device__ __forceinline__ int rowbase(int a){
  return (a < 4) ? a*16 : (a < 8) ? 64 + (a - 4)*16 : 128 + (a - 8)*16;
}

// One GRU step. aug path fp32 VALU, weights read from block-shared LDS
// (saves ~40 arch VGPRs -> unified VGPR+AGPR total fits 3 waves/SIMD).
// h-part: single fp16 MFMA per (a,kt), B-tiles in LDS, hb fp16 transpose.
__device__ __forceinline__ void run_step(
    const float x0[4], const float x1[4],
    const _Float16* __restrict__ tiles, const float* __restrict__ auw,
    float hc[16], half8 ahi[2], _Float16* hb,
    int c15, int quad, int lane8)
{
  f32x4 acc[12];
  #pragma unroll
  for (int a = 0; a < 8; ++a){
    const int j = (a & 3)*16 + c15 + (a >= 4 ? 64 : 0);
    const float w0 = auw[j], w1 = auw[192 + j], bb = auw[384 + j];
    #pragma unroll
    for (int r = 0; r < 4; ++r)
      acc[a][r] = fmaf(x0[r], w0, fmaf(x1[r], w1, bb));
  }
  #pragma unroll
  for (int a = 8; a < 12; ++a){
    const float bb = auw[576 + (a - 8)*16 + c15];
    #pragma unroll
    for (int r = 0; r < 4; ++r) acc[a][r] = bb;
  }
  #pragma unroll
  for (int a = 0; a < 12; ++a){
    #pragma unroll
    for (int kt = 0; kt < 2; ++kt){
      const half8 bh = *(const half8*)(tiles + (a*2 + kt)*512 + lane8);
      acc[a] = MFMAH(ahi[kt], bh, acc[a]);
    }
  }
  // gates (gx_n inline fp32) + fp16 transpose via hb
  #pragma unroll
  for (int q = 0; q < 4; ++q){
    const int j = 128 + q*16 + c15;
    const float gw0 = auw[j], gw1 = auw[192 + j], gb = auw[384 + j];
    #pragma unroll
    for (int r = 0; r < 4; ++r){
      const float pr = acc[q][r], pz = acc[4 + q][r], gh = acc[8 + q][r];
      const float gx = fmaf(x0[r], gw0, fmaf(x1[r], gw1, gb));
      const float rr = sigm(pr), zz = sigm(pz);
      const float nn = tanh_f(fmaf(rr, gh, gx));
      const float hn = (1.0f - zz)*nn + zz*hc[q*4 + r];
      hc[q*4 + r] = hn;
      hb[(quad*4 + r)*72 + q*16 + c15] = (_Float16)hn;
    }
  }
  #pragma unroll
  for (int kt = 0; kt < 2; ++kt)
    ahi[kt] = *(const half8*)&hb[c15*72 + kt*32 + quad*8];
}

__global__ __launch_bounds__(256, 2) void rnn_mfma8(
    const float* __restrict__ X, W wp, float* __restrict__ out)
{
  __shared__ __align__(16) _Float16 tiles_s[26*512];   // 24 whh tiles + 2 hv/v
  __shared__ __align__(16) _Float16 hbuf_s[4*1152];    // per-wave fp16 hb (16x72)
  __shared__ __align__(16) float wbuf_s[4*624];        // per-wave hv/va/lvb
  __shared__ __align__(16) float auw_s[640];           // block-shared aug weights

  const int tid = threadIdx.x;
  const int wid = tid >> 6, lane = tid & 63;
  const int quad = lane >> 4, c15 = lane & 15;
  const int lane8 = lane*8;
  _Float16* hb = hbuf_s + wid*1152;
  float* wl  = wbuf_s + wid*624;
  float* hv  = wl;                 // 16*26
  float* va  = wl + 416;           // 16*12
  float* lvb = wl + 608;           // 16
  const int wavebase = (blockIdx.x*4 + wid)*16;

  // ---- X row -> regs: lane holds sample m=c15, elements [quad*8, quad*8+8) ----
  float xr[8];
  if (quad < 3){
    const float* xp = X + (size_t)(wavebase + c15)*24 + quad*8;
    f32x4 p0 = *(const f32x4*)xp, p1 = *(const f32x4*)(xp + 4);
    xr[0]=p0[0]; xr[1]=p0[1]; xr[2]=p0[2]; xr[3]=p0[3];
    xr[4]=p1[0]; xr[5]=p1[1]; xr[6]=p1[2]; xr[7]=p1[3];
  } else {
    #pragma unroll
    for (int i = 0; i < 8; ++i) xr[i] = 0.f;
  }
  const float lastv = X[(size_t)(wavebase + c15)*24 + 22];

  // w0[o] = sum_t query[t]*emb[t][o]; quad q holds t in [4q,4q+4) -> shfl reduce
  float w0[TOUT];
  #pragma unroll
  for (int o = 0; o < TOUT; ++o) w0[o] = 0.f;
  if (quad < 3){
    #pragma unroll
    for (int tt = 0; tt < 4; ++tt){
      const int t = quad*4 + tt;
      const float qv = xr[2*tt];
      #pragma unroll
      for (int o = 0; o < TOUT; ++o) w0[o] = fmaf(qv, wp.emb[t*TOUT + o], w0[o]);
    }
  }
  #pragma unroll
  for (int o = 0; o < TOUT; ++o){
    w0[o] += __shfl_xor(w0[o], 16, 64);
    w0[o] += __shfl_xor(w0[o], 32, 64);
  }

  // A-frag for hv GEMM (quad3 = exact-1.0 bias row k=24)
  half8 axh = {0,0,0,0,0,0,0,0};
  if (quad < 3){
    #pragma unroll
    for (int j2 = 0; j2 < 8; ++j2) axh[j2] = (_Float16)xr[j2];
  } else {
    axh[0] = (_Float16)1.0f;
  }

  float msx = -1e30f, dsum = 0.f;
  float num[TOUT];
  #pragma unroll
  for (int o = 0; o < TOUT; ++o) num[o] = 0.f;

  #pragma unroll 1
  for (int c = 0; c < CC; ++c){
    const float l1b = wp.l1b[c];

    // ======== encoder phase ========
    __syncthreads();
    {
      const float* whh = wp.ewhh + c*12288;
      for (int ch = tid; ch < 24*64; ch += 256){
        const int tile = ch >> 6, L = ch & 63;
        const int a = tile >> 1, kt = tile & 1;
        const int col = L & 15, qd = L >> 4;
        const float* src = whh + (rowbase(a) + col)*64 + kt*32 + qd*8;
        f32x4 p0 = *(const f32x4*)src, p1 = *(const f32x4*)(src + 4);
        half8 h;
        h[0]=(_Float16)p0[0]; h[1]=(_Float16)p0[1]; h[2]=(_Float16)p0[2]; h[3]=(_Float16)p0[3];
        h[4]=(_Float16)p1[0]; h[5]=(_Float16)p1[1]; h[6]=(_Float16)p1[2]; h[7]=(_Float16)p1[3];
        *(half8*)(tiles_s + tile*512 + L*8) = h;
      }
      // hv tiles from l2w/l2b: slot 24+nt; B[k=2t+f2][col] = (f2==f)*w2[j][t], row24=b2[j]
      for (int ch = tid; ch < 2*64; ch += 256){
        const int nt = ch >> 6, L = ch & 63;
        const int col = L & 15, qd = L >> 4;
        const int j_ = nt*8 + (col >> 1), f_ = col & 1;
        const bool okc = (nt == 0) || (col < 8);
        half8 h;
        #pragma unroll
        for (int jj = 0; jj < 8; ++jj){
          const int k = qd*8 + jj;
          float v = 0.f;
          if (okc){
            if (k < 24){
              const int t = k >> 1, f2 = k & 1;
              if (f2 == f_) v = wp.l2w[c*144 + j_*12 + t];
            } else if (k == 24){
              v = wp.l2b[c*12 + j_];
            }
          }
          h[jj] = (_Float16)v;
        }
        *(half8*)(tiles_s + (24 + nt)*512 + L*8) = h;
      }
      // enc aug weights -> block-shared LDS
      for (int j = tid; j < 192; j += 256){
        auw_s[j]       = wp.ewih[c*384 + 2*j];
        auw_s[192 + j] = wp.ewih[c*384 + 2*j + 1];
        auw_s[384 + j] = wp.ebih[c*192 + j] + (j < 128 ? wp.ebhh[c*192 + j] : 0.f);
        if (j >= 128) auw_s[576 + (j - 128)] = wp.ebhh[c*192 + j];
      }
    }
    __syncthreads();

    // hv GEMM: inputs for all 12 encoder steps
    #pragma unroll
    for (int nt = 0; nt < 2; ++nt){
      f32x4 a = {0.f, 0.f, 0.f, 0.f};
      const half8 bh = *(const half8*)(tiles_s + (24 + nt)*512 + lane8);
      a = MFMAH(axh, bh, a);
      if (nt == 0 || c15 < 8){
        #pragma unroll
        for (int r = 0; r < 4; ++r)
          hv[(quad*4 + r)*26 + nt*16 + c15] = a[r];
      }
    }

    float hc[16];
    #pragma unroll
    for (int q = 0; q < 16; ++q) hc[q] = 0.f;
    half8 ahi[2];
    ahi[0] = (half8){0,0,0,0,0,0,0,0};
    ahi[1] = (half8){0,0,0,0,0,0,0,0};

    const int steps = 3 + c;
    #pragma unroll 1
    for (int j = 0; j < steps; ++j){
      float x0[4], x1[4];
      #pragma unroll
      for (int r = 0; r < 4; ++r){
        const float2 p = *(const float2*)&hv[(quad*4 + r)*26 + 2*j];
        x0[r] = p.x; x1[r] = p.y;
      }
      run_step(x0, x1, tiles_s, auw_s, hc, ahi, hb, c15, quad, lane8);
    }

    // ======== decoder phase ========
    __syncthreads();
    {
      const float* whh = wp.dwhh + c*12288;
      for (int ch = tid; ch < 24*64; ch += 256){
        const int tile = ch >> 6, L = ch & 63;
        const int a = tile >> 1, kt = tile & 1;
        const int col = L & 15, qd = L >> 4;
        const float* src = whh + (rowbase(a) + col)*64 + kt*32 + qd*8;
        f32x4 p0 = *(const f32x4*)src, p1 = *(const f32x4*)(src + 4);
        half8 h;
        h[0]=(_Float16)p0[0]; h[1]=(_Float16)p0[1]; h[2]=(_Float16)p0[2]; h[3]=(_Float16)p0[3];
        h[4]=(_Float16)p1[0]; h[5]=(_Float16)p1[1]; h[6]=(_Float16)p1[2]; h[7]=(_Float16)p1[3];
        *(half8*)(tiles_s + tile*512 + L*8) = h;
      }
      // v tiles (l1w in col 0): slots 24..25
      for (int ch = tid; ch < 2*64; ch += 256){
        const int kt = ch >> 6, L = ch & 63;
        const int col = L & 15, qd = L >> 4;
        half8 h = {0,0,0,0,0,0,0,0};
        if (col == 0){
          const float* src = wp.l1w + c*64 + kt*32 + qd*8;
          f32x4 p0 = *(const f32x4*)src, p1 = *(const f32x4*)(src + 4);
          h[0]=(_Float16)p0[0]; h[1]=(_Float16)p0[1]; h[2]=(_Float16)p0[2]; h[3]=(_Float16)p0[3];
          h[4]=(_Float16)p1[0]; h[5]=(_Float16)p1[1]; h[6]=(_Float16)p1[2]; h[7]=(_Float16)p1[3];
        }
        *(half8*)(tiles_s + (24 + kt)*512 + L*8) = h;
      }
      // dec aug weights -> block-shared LDS
      for (int j = tid; j < 192; j += 256){
        auw_s[j]       = wp.dwih[c*192 + j];
        auw_s[192 + j] = 0.f;
        auw_s[384 + j] = wp.dbih[c*192 + j] + (j < 128 ? wp.dbhh[c*192 + j] : 0.f);
        if (j >= 128) auw_s[576 + (j - 128)] = wp.dbhh[c*192 + j];
      }
    }
    __syncthreads();

    if (quad == 0) lvb[c15] = lastv;

    const float zx1[4] = {0.f, 0.f, 0.f, 0.f};
    #pragma unroll 1
    for (int i = 0; i < TOUT; ++i){
      if (i > 0){
        f32x4 accv = {l1b, l1b, l1b, l1b};
        #pragma unroll
        for (int kt = 0; kt < 2; ++kt){
          const half8 bh = *(const half8*)(tiles_s + (24 + kt)*512 + lane8);
          accv = MFMAH(ahi[kt], bh, accv);
        }
        if (c15 == 0){
          #pragma unroll
          for (int r = 0; r < 4; ++r){
            va[(quad*4 + r)*12 + (i - 1)] = accv[r];
            lvb[quad*4 + r] = accv[r];
          }
        }
      }
      float x0[4];
      #pragma unroll
      for (int r = 0; r < 4; ++r) x0[r] = lvb[quad*4 + r];
      run_step(x0, zx1, tiles_s, auw_s, hc, ahi, hb, c15, quad, lane8);
    }
    {
      f32x4 accv = {l1b, l1b, l1b, l1b};
      #pragma unroll
      for (int kt = 0; kt < 2; ++kt){
        const half8 bh = *(const half8*)(tiles_s + (24 + kt)*512 + lane8);
        accv = MFMAH(ahi[kt], bh, accv);
      }
      if (c15 == 0){
        #pragma unroll
        for (int r = 0; r < 4; ++r) va[(quad*4 + r)*12 + 11] = accv[r];
      }
    }

    // online softmax update (per-lane, m=c15)
    {
      float l = 0.f;
      #pragma unroll
      for (int o = 0; o < TOUT; ++o) l = fmaf(w0[o], va[c15*12 + o], l);
      const float nmx = fmaxf(msx, l);
      const float aa = __expf(msx - nmx);
      const float ee = __expf(l - nmx);
      dsum = dsum*aa + ee;
      #pragma unroll
      for (int o = 0; o < TOUT; ++o) num[o] = num[o]*aa + va[c15*12 + o]*ee;
      msx = nmx;
    }
  }

  if (quad == 0){
    const float inv = 1.0f / dsum;
    #pragma unroll
    for (int o = 0; o < TOUT; ++o)
      out[(size_t)(wavebase + c15)*12 + o] = num[o]*inv;
  }
}

extern "C" void kernel_launch(void* const* d_in, const int* in_sizes, int n_in,
                              void* d_out, int out_size, void* d_ws, size_t ws_size,
                              hipStream_t stream) {
  int iX = 1, iW = 2;
  for (int i = 0; i < n_in; ++i){
    if (in_sizes[i] == 3145728) iX = i;
    if (in_sizes[i] == 3840)   { iW = i; break; }
  }
  W wp;
  wp.ewih = (const float*)d_in[iW + 0];
  wp.ewhh = (const float*)d_in[iW + 1];
  wp.ebih = (const float*)d_in[iW + 2];
  wp.ebhh = (const float*)d_in[iW + 3];
  wp.dwih = (const float*)d_in[iW + 4];
  wp.dwhh = (const float*)d_in[iW + 5];
  wp.dbih = (const float*)d_in[iW + 6];
  wp.dbhh = (const float*)d_in[iW + 7];
  wp.l1w  = (const float*)d_in[iW + 8];
  wp.l1b  = (const float*)d_in[iW + 9];
  wp.l2w  = (const float*)d_in[iW + 10];
  wp.l2b  = (const float*)d_in[iW + 11];
  wp.emb  = (const float*)d_in[iW + 12];

  rnn_mfma8<<<BNTOT / 64, 256, 0, stream>>>(
      (const float*)d_in[iX], wp, (float*)d_out);
}